// Round 1
// baseline (2484.344 us; speedup 1.0000x reference)
//
#include <hip/hip_runtime.h>
#include <cmath>

#define BB 2
#define SS 2048
#define DD 1024
#define HH 16
#define HDIM 64
#define KDIM 1024
#define EPSF 1e-8f

// ---------------------------------------------------------------------------
// Kernel 1: QKV projection (A @ W^T) with fused RoPE epilogue.
// A: (B*S, D) row-major. W: (D, D) row-major (output col j uses W row j).
// Output layout: (B, H, S, HD) for attention-friendly access.
// blockIdx.z selects {wq, wk, wv}. 64x64 tile, 16 k-slab, 4x4 per thread.
// ---------------------------------------------------------------------------
__global__ __launch_bounds__(256) void gemm_qkv_rope(
    const float* __restrict__ A,
    const float* __restrict__ wq, const float* __restrict__ wk,
    const float* __restrict__ wv,
    const float* __restrict__ sinp, const float* __restrict__ cosp,
    float* __restrict__ Qr, float* __restrict__ Kr, float* __restrict__ Vr)
{
    const float* W = (blockIdx.z == 0) ? wq : (blockIdx.z == 1) ? wk : wv;
    float* O = (blockIdx.z == 0) ? Qr : (blockIdx.z == 1) ? Kr : Vr;

    __shared__ float As[64][17];   // +1 pad: conflict-free micro-tile reads
    __shared__ float Ws[64][17];

    const int tid = threadIdx.x;
    const int tx = tid % 16, ty = tid / 16;
    const int row0 = blockIdx.x * 64;
    const int col0 = blockIdx.y * 64;

    const int lr = tid / 4;          // 0..63 staging row
    const int lc = (tid % 4) * 4;    // 0,4,8,12 staging k-col

    float acc[4][4] = {};

    for (int k0 = 0; k0 < KDIM; k0 += 16) {
        float4 a4 = *(const float4*)(A + (size_t)(row0 + lr) * KDIM + k0 + lc);
        float4 w4 = *(const float4*)(W + (size_t)(col0 + lr) * KDIM + k0 + lc);
        As[lr][lc + 0] = a4.x; As[lr][lc + 1] = a4.y;
        As[lr][lc + 2] = a4.z; As[lr][lc + 3] = a4.w;
        Ws[lr][lc + 0] = w4.x; Ws[lr][lc + 1] = w4.y;
        Ws[lr][lc + 2] = w4.z; Ws[lr][lc + 3] = w4.w;
        __syncthreads();
#pragma unroll
        for (int kk = 0; kk < 16; ++kk) {
            float a[4], w[4];
#pragma unroll
            for (int i = 0; i < 4; ++i) a[i] = As[ty * 4 + i][kk];
#pragma unroll
            for (int j = 0; j < 4; ++j) w[j] = Ws[tx * 4 + j][kk];
#pragma unroll
            for (int i = 0; i < 4; ++i)
#pragma unroll
                for (int j = 0; j < 4; ++j) acc[i][j] += a[i] * w[j];
        }
        __syncthreads();
    }

    // Epilogue: rotary on adjacent column pairs (cols are even-aligned per
    // thread since tx*4 is even), scatter to (B,H,S,HD).
#pragma unroll
    for (int i = 0; i < 4; ++i) {
        const int t = row0 + ty * 4 + i;
        const int b = t / SS, s = t % SS;
#pragma unroll
        for (int p = 0; p < 2; ++p) {
            const int c = col0 + tx * 4 + p * 2;
            const int h = c / HDIM, e = c % HDIM;
            const float sv = sinp[s * (HDIM / 2) + e / 2];
            const float cv = cosp[s * (HDIM / 2) + e / 2];
            const float x1 = acc[i][p * 2], x2 = acc[i][p * 2 + 1];
            const size_t dst = ((size_t)(b * HH + h) * SS + s) * HDIM + e;
            O[dst]     = x1 * cv - x2 * sv;
            O[dst + 1] = x2 * cv + x1 * sv;
        }
    }
}

// ---------------------------------------------------------------------------
// Kernel 2: flash-style attention. Block = 256 threads = (b,h) x 32 q-rows.
// Streams 64-wide K/V tiles through LDS with online softmax; never
// materializes the 2048x2048 score matrix. Thread t owns q-row t/8 and
// 8 k-columns / 8 output dims (group g = t%8, within one wave).
// ---------------------------------------------------------------------------
__global__ __launch_bounds__(256) void attn_kernel(
    const float* __restrict__ Q, const float* __restrict__ K,
    const float* __restrict__ V, float* __restrict__ ctx)
{
    const int bh = blockIdx.y;          // 0..B*H-1
    const int b = bh / HH, h = bh % HH;
    const int q0 = blockIdx.x * 32;
    const float* Qh = Q + (size_t)bh * SS * HDIM;
    const float* Kh = K + (size_t)bh * SS * HDIM;
    const float* Vh = V + (size_t)bh * SS * HDIM;

    __shared__ float qs[32][HDIM + 1];
    __shared__ float ks[64][HDIM + 1];
    __shared__ float vs[64][HDIM + 1];
    __shared__ float ps[32][64 + 1];

    const int tid = threadIdx.x;

    // load q tile: 32x64 floats, 8 per thread (2x float4)
#pragma unroll
    for (int it = 0; it < 2; ++it) {
        const int idx = (tid + it * 256) * 4;
        const int r = idx / HDIM, c = idx % HDIM;
        float4 v4 = *(const float4*)(Qh + (size_t)(q0 + r) * HDIM + c);
        qs[r][c] = v4.x; qs[r][c + 1] = v4.y;
        qs[r][c + 2] = v4.z; qs[r][c + 3] = v4.w;
    }

    const int r = tid / 8;     // q-row within tile (0..31)
    const int g = tid % 8;     // group lane
    const int c0 = g * 8;
    float m_i = -INFINITY, l_i = 0.f;
    float Oacc[8] = {0.f, 0.f, 0.f, 0.f, 0.f, 0.f, 0.f, 0.f};

    __syncthreads();

    for (int k0 = 0; k0 < SS; k0 += 64) {
        // stage K/V tile: 64x64 each, 16 floats/thread each
#pragma unroll
        for (int it = 0; it < 4; ++it) {
            const int idx = (tid + it * 256) * 4;
            const int kr = idx / HDIM, kc = idx % HDIM;
            float4 kv = *(const float4*)(Kh + (size_t)(k0 + kr) * HDIM + kc);
            float4 vv = *(const float4*)(Vh + (size_t)(k0 + kr) * HDIM + kc);
            ks[kr][kc] = kv.x; ks[kr][kc + 1] = kv.y;
            ks[kr][kc + 2] = kv.z; ks[kr][kc + 3] = kv.w;
            vs[kr][kc] = vv.x; vs[kr][kc + 1] = vv.y;
            vs[kr][kc + 2] = vv.z; vs[kr][kc + 3] = vv.w;
        }
        __syncthreads();

        // scores: 8 per thread (k = c0..c0+7)
        float sc[8] = {0.f, 0.f, 0.f, 0.f, 0.f, 0.f, 0.f, 0.f};
        for (int e = 0; e < HDIM; ++e) {
            const float qv = qs[r][e];
#pragma unroll
            for (int j = 0; j < 8; ++j) sc[j] += qv * ks[c0 + j][e];
        }
        float mx = -INFINITY;
#pragma unroll
        for (int j = 0; j < 8; ++j) { sc[j] *= 0.125f; mx = fmaxf(mx, sc[j]); }
#pragma unroll
        for (int off = 1; off < 8; off <<= 1) mx = fmaxf(mx, __shfl_xor(mx, off));
        const float m_new = fmaxf(m_i, mx);
        const float alpha = __expf(m_i - m_new);   // exp(-inf)=0 on first tile
        float lsum = 0.f;
#pragma unroll
        for (int j = 0; j < 8; ++j) {
            const float p = __expf(sc[j] - m_new);
            ps[r][c0 + j] = p;
            lsum += p;
        }
#pragma unroll
        for (int off = 1; off < 8; off <<= 1) lsum += __shfl_xor(lsum, off);
        l_i = l_i * alpha + lsum;
        m_i = m_new;
#pragma unroll
        for (int j = 0; j < 8; ++j) Oacc[j] *= alpha;
        __syncthreads();   // safety barrier: ps visible before PV

        // PV: O[r][c0+j] += sum_k p[r][k] * v[k][c0+j]
        for (int k = 0; k < 64; ++k) {
            const float pv = ps[r][k];
#pragma unroll
            for (int j = 0; j < 8; ++j) Oacc[j] += pv * vs[k][c0 + j];
        }
        __syncthreads();   // before next tile overwrites ks/vs
    }

    const float inv_l = 1.f / l_i;
    const int s = q0 + r;
    const size_t base = ((size_t)(b * SS + s)) * DD + h * HDIM + c0;
#pragma unroll
    for (int j = 0; j < 8; ++j) ctx[base + j] = Oacc[j] * inv_l;
}

// ---------------------------------------------------------------------------
// Kernel 3: output projection ctx @ wo^T + bo -> (B*S, D) row-major.
// ---------------------------------------------------------------------------
__global__ __launch_bounds__(256) void gemm_out(
    const float* __restrict__ A, const float* __restrict__ W,
    const float* __restrict__ bias, float* __restrict__ Out)
{
    __shared__ float As[64][17];
    __shared__ float Ws[64][17];

    const int tid = threadIdx.x;
    const int tx = tid % 16, ty = tid / 16;
    const int row0 = blockIdx.x * 64;
    const int col0 = blockIdx.y * 64;

    const int lr = tid / 4;
    const int lc = (tid % 4) * 4;

    float acc[4][4] = {};

    for (int k0 = 0; k0 < KDIM; k0 += 16) {
        float4 a4 = *(const float4*)(A + (size_t)(row0 + lr) * KDIM + k0 + lc);
        float4 w4 = *(const float4*)(W + (size_t)(col0 + lr) * KDIM + k0 + lc);
        As[lr][lc + 0] = a4.x; As[lr][lc + 1] = a4.y;
        As[lr][lc + 2] = a4.z; As[lr][lc + 3] = a4.w;
        Ws[lr][lc + 0] = w4.x; Ws[lr][lc + 1] = w4.y;
        Ws[lr][lc + 2] = w4.z; Ws[lr][lc + 3] = w4.w;
        __syncthreads();
#pragma unroll
        for (int kk = 0; kk < 16; ++kk) {
            float a[4], w[4];
#pragma unroll
            for (int i = 0; i < 4; ++i) a[i] = As[ty * 4 + i][kk];
#pragma unroll
            for (int j = 0; j < 4; ++j) w[j] = Ws[tx * 4 + j][kk];
#pragma unroll
            for (int i = 0; i < 4; ++i)
#pragma unroll
                for (int j = 0; j < 4; ++j) acc[i][j] += a[i] * w[j];
        }
        __syncthreads();
    }

#pragma unroll
    for (int i = 0; i < 4; ++i) {
        const int t = row0 + ty * 4 + i;
#pragma unroll
        for (int j = 0; j < 4; ++j) {
            const int c = col0 + tx * 4 + j;
            Out[(size_t)t * DD + c] = acc[i][j] + bias[c];
        }
    }
}

// ---------------------------------------------------------------------------
// Kernel 4: residual add + RMSNorm. One block per token.
// rms = sqrt(mean(x^2)); out = scale * x / (rms + eps)
// ---------------------------------------------------------------------------
__global__ __launch_bounds__(256) void resid_rmsnorm(
    const float* __restrict__ proj, const float* __restrict__ hs,
    const float* __restrict__ scale, float* __restrict__ out)
{
    const int t = blockIdx.x;
    const int tid = threadIdx.x;
    const size_t base = (size_t)t * DD + tid * 4;

    const float4 p4 = *(const float4*)(proj + base);
    const float4 h4 = *(const float4*)(hs + base);
    float x0 = p4.x + h4.x, x1 = p4.y + h4.y, x2 = p4.z + h4.z, x3 = p4.w + h4.w;
    float ss = x0 * x0 + x1 * x1 + x2 * x2 + x3 * x3;

#pragma unroll
    for (int off = 1; off < 64; off <<= 1) ss += __shfl_xor(ss, off);

    __shared__ float wsum[4];
    if ((tid & 63) == 0) wsum[tid >> 6] = ss;
    __syncthreads();
    const float total = wsum[0] + wsum[1] + wsum[2] + wsum[3];
    const float inv = 1.f / (sqrtf(total * (1.f / DD)) + EPSF);

    const float4 s4 = *(const float4*)(scale + tid * 4);
    float4 o;
    o.x = s4.x * x0 * inv;
    o.y = s4.y * x1 * inv;
    o.z = s4.z * x2 * inv;
    o.w = s4.w * x3 * inv;
    *(float4*)(out + base) = o;
}

// ---------------------------------------------------------------------------
extern "C" void kernel_launch(void* const* d_in, const int* in_sizes, int n_in,
                              void* d_out, int out_size, void* d_ws, size_t ws_size,
                              hipStream_t stream) {
    const float* hs    = (const float*)d_in[0];  // (B,S,D)
    const float* sinp  = (const float*)d_in[1];  // (1,1,S,HD/2)
    const float* cosp  = (const float*)d_in[2];
    const float* wq    = (const float*)d_in[3];
    const float* wk    = (const float*)d_in[4];
    const float* wv    = (const float*)d_in[5];
    const float* wo    = (const float*)d_in[6];
    const float* bo    = (const float*)d_in[7];
    const float* scale = (const float*)d_in[8];
    float* out = (float*)d_out;
    float* ws  = (float*)d_ws;

    const size_t MAT = (size_t)BB * SS * DD;   // 4,194,304 floats = 16 MB
    float* Qr   = ws;             // (B,H,S,HD) rotated
    float* Kr   = ws + MAT;
    float* Vr   = ws + 2 * MAT;
    float* ctxb = ws + 3 * MAT;   // (B,S,D)
    float* proj = ws + 4 * MAT;   // (B,S,D)
    // total ws use: 80 MB

    gemm_qkv_rope<<<dim3(64, 16, 3), 256, 0, stream>>>(hs, wq, wk, wv, sinp, cosp,
                                                       Qr, Kr, Vr);
    attn_kernel<<<dim3(SS / 32, BB * HH), 256, 0, stream>>>(Qr, Kr, Vr, ctxb);
    gemm_out<<<dim3(64, 16), 256, 0, stream>>>(ctxb, wo, bo, proj);
    resid_rmsnorm<<<dim3(BB * SS), 256, 0, stream>>>(proj, hs, scale, out);
}

// Round 2
// 1051.764 us; speedup vs baseline: 2.3621x; 2.3621x over previous
//
#include <hip/hip_runtime.h>
#include <cmath>

#define BB 2
#define SS 2048
#define DD 1024
#define HH 16
#define HDIM 64
#define KDIM 1024
#define EPSF 1e-8f

typedef __attribute__((ext_vector_type(8))) short bf16x8;
typedef __attribute__((ext_vector_type(4))) float f32x4;

__device__ __forceinline__ ushort f2bf(float x) {
    unsigned u = __builtin_bit_cast(unsigned, x);
    u += 0x7FFFu + ((u >> 16) & 1u);   // RNE
    return (ushort)(u >> 16);
}

// ---------------------------------------------------------------------------
// Kernel 1: QKV projection (A @ W^T) with fused RoPE epilogue, bf16 outputs.
// Q,K -> (B,H,S,HD) bf16.  V -> transposed (B,H,HD,S) bf16 so the attention
// PV B-fragment is a contiguous 16-byte load.
// ---------------------------------------------------------------------------
__global__ __launch_bounds__(256) void gemm_qkv_rope(
    const float* __restrict__ A,
    const float* __restrict__ wq, const float* __restrict__ wk,
    const float* __restrict__ wv,
    const float* __restrict__ sinp, const float* __restrict__ cosp,
    ushort* __restrict__ Qb, ushort* __restrict__ Kb, ushort* __restrict__ Vtb)
{
    const float* W = (blockIdx.z == 0) ? wq : (blockIdx.z == 1) ? wk : wv;
    ushort* O = (blockIdx.z == 0) ? Qb : (blockIdx.z == 1) ? Kb : Vtb;

    __shared__ float As[64][17];
    __shared__ float Ws[64][17];

    const int tid = threadIdx.x;
    const int tx = tid % 16, ty = tid / 16;
    const int row0 = blockIdx.x * 64;
    const int col0 = blockIdx.y * 64;

    const int lr = tid / 4;
    const int lc = (tid % 4) * 4;

    float acc[4][4] = {};

    for (int k0 = 0; k0 < KDIM; k0 += 16) {
        float4 a4 = *(const float4*)(A + (size_t)(row0 + lr) * KDIM + k0 + lc);
        float4 w4 = *(const float4*)(W + (size_t)(col0 + lr) * KDIM + k0 + lc);
        As[lr][lc + 0] = a4.x; As[lr][lc + 1] = a4.y;
        As[lr][lc + 2] = a4.z; As[lr][lc + 3] = a4.w;
        Ws[lr][lc + 0] = w4.x; Ws[lr][lc + 1] = w4.y;
        Ws[lr][lc + 2] = w4.z; Ws[lr][lc + 3] = w4.w;
        __syncthreads();
#pragma unroll
        for (int kk = 0; kk < 16; ++kk) {
            float a[4], w[4];
#pragma unroll
            for (int i = 0; i < 4; ++i) a[i] = As[ty * 4 + i][kk];
#pragma unroll
            for (int j = 0; j < 4; ++j) w[j] = Ws[tx * 4 + j][kk];
#pragma unroll
            for (int i = 0; i < 4; ++i)
#pragma unroll
                for (int j = 0; j < 4; ++j) acc[i][j] += a[i] * w[j];
        }
        __syncthreads();
    }

#pragma unroll
    for (int i = 0; i < 4; ++i) {
        const int t = row0 + ty * 4 + i;
        const int b = t / SS, s = t % SS;
#pragma unroll
        for (int p = 0; p < 2; ++p) {
            const int c = col0 + tx * 4 + p * 2;
            const int h = c / HDIM, e = c % HDIM;
            const float sv = sinp[s * (HDIM / 2) + e / 2];
            const float cv = cosp[s * (HDIM / 2) + e / 2];
            const float x1 = acc[i][p * 2], x2 = acc[i][p * 2 + 1];
            const float o1 = x1 * cv - x2 * sv;
            const float o2 = x2 * cv + x1 * sv;
            const int bh = b * HH + h;
            if (blockIdx.z < 2) {
                const unsigned pk = (unsigned)f2bf(o1) | ((unsigned)f2bf(o2) << 16);
                *(unsigned*)(O + ((size_t)(bh * SS + s)) * HDIM + e) = pk;
            } else {
                O[((size_t)(bh * HDIM + e)) * SS + s]     = f2bf(o1);
                O[((size_t)(bh * HDIM + e + 1)) * SS + s] = f2bf(o2);
            }
        }
    }
}

// ---------------------------------------------------------------------------
// Kernel 2: flash attention with bf16 MFMA (16x16x32).
// Block = 4 waves = 64 q-rows; wave w owns q-rows [q0+16w, q0+16w+16).
// Per 64-key tile: scores via 4x2 MFMA (C layout: col=lane&15,
// row=quad*4+reg), online softmax in registers (quad-wide shfl reductions),
// P round-trips through wave-private LDS rows to reach A-operand layout,
// PV via 2x4 MFMA against transposed-V. No __syncthreads needed: every LDS
// row is wave-private and DS ops are in-order per wave.
// ---------------------------------------------------------------------------
__global__ __launch_bounds__(256) void attn_mfma(
    const ushort* __restrict__ Qb, const ushort* __restrict__ Kb,
    const ushort* __restrict__ Vtb, float* __restrict__ ctx)
{
    const int bh = blockIdx.y;
    const int b = bh / HH, h = bh % HH;
    const int q0 = blockIdx.x * 64;
    const int tid = threadIdx.x;
    const int w = tid >> 6;
    const int lane = tid & 63;
    const int quad = lane >> 4;
    const int l15 = lane & 15;

    __shared__ __align__(16) float ps[64][68];   // +4 pad: 2-way banks max

    const ushort* Qh = Qb  + (size_t)bh * SS * HDIM;
    const ushort* Kh = Kb  + (size_t)bh * SS * HDIM;
    const ushort* Vh = Vtb + (size_t)bh * HDIM * SS;

    const int qrow = q0 + w * 16 + l15;
    const bf16x8 qf0 = *(const bf16x8*)(Qh + (size_t)qrow * HDIM + quad * 8);
    const bf16x8 qf1 = *(const bf16x8*)(Qh + (size_t)qrow * HDIM + 32 + quad * 8);

    f32x4 cacc[4] = {{0,0,0,0},{0,0,0,0},{0,0,0,0},{0,0,0,0}};
    float m_i[4] = {-INFINITY, -INFINITY, -INFINITY, -INFINITY};
    float l_i[4] = {0.f, 0.f, 0.f, 0.f};

    for (int k0 = 0; k0 < SS; k0 += 64) {
        // ---- scores: S = Q K^T (4 col-tiles x 2 k-steps) ----
        f32x4 sacc[4];
#pragma unroll
        for (int n0 = 0; n0 < 4; ++n0) {
            const ushort* kr = Kh + (size_t)(k0 + n0 * 16 + l15) * HDIM + quad * 8;
            const bf16x8 kf0 = *(const bf16x8*)(kr);
            const bf16x8 kf1 = *(const bf16x8*)(kr + 32);
            f32x4 s = {0.f, 0.f, 0.f, 0.f};
            s = __builtin_amdgcn_mfma_f32_16x16x32_bf16(qf0, kf0, s, 0, 0, 0);
            s = __builtin_amdgcn_mfma_f32_16x16x32_bf16(qf1, kf1, s, 0, 0, 0);
            sacc[n0] = s;
        }
        // ---- online softmax (per row r = quad*4 + reg) ----
#pragma unroll
        for (int r = 0; r < 4; ++r) {
            float mx = fmaxf(fmaxf(sacc[0][r], sacc[1][r]),
                             fmaxf(sacc[2][r], sacc[3][r]));
#pragma unroll
            for (int off = 1; off < 16; off <<= 1) mx = fmaxf(mx, __shfl_xor(mx, off));
            const float mnew = fmaxf(m_i[r], mx * 0.125f);
            const float alpha = __expf(m_i[r] - mnew);   // first tile: exp(-inf)=0
            float ls = 0.f;
#pragma unroll
            for (int n0 = 0; n0 < 4; ++n0) {
                const float p = __expf(sacc[n0][r] * 0.125f - mnew);
                ps[w * 16 + quad * 4 + r][n0 * 16 + l15] = p;
                ls += p;
            }
#pragma unroll
            for (int off = 1; off < 16; off <<= 1) ls += __shfl_xor(ls, off);
            l_i[r] = l_i[r] * alpha + ls;
            m_i[r] = mnew;
#pragma unroll
            for (int d0 = 0; d0 < 4; ++d0) cacc[d0][r] *= alpha;
        }
        // ---- PV: ctx += P V (A-layout reload of P from LDS) ----
#pragma unroll
        for (int step = 0; step < 2; ++step) {
            const float* pr = &ps[w * 16 + l15][step * 32 + quad * 8];
            const float4 p0 = *(const float4*)(pr);
            const float4 p1 = *(const float4*)(pr + 4);
            union { ushort us[8]; bf16x8 v; } pu;
            pu.us[0] = f2bf(p0.x); pu.us[1] = f2bf(p0.y);
            pu.us[2] = f2bf(p0.z); pu.us[3] = f2bf(p0.w);
            pu.us[4] = f2bf(p1.x); pu.us[5] = f2bf(p1.y);
            pu.us[6] = f2bf(p1.z); pu.us[7] = f2bf(p1.w);
#pragma unroll
            for (int d0 = 0; d0 < 4; ++d0) {
                const bf16x8 vf = *(const bf16x8*)(
                    Vh + (size_t)(d0 * 16 + l15) * SS + k0 + step * 32 + quad * 8);
                cacc[d0] = __builtin_amdgcn_mfma_f32_16x16x32_bf16(pu.v, vf, cacc[d0], 0, 0, 0);
            }
        }
    }

    // epilogue: normalize by l, scatter to (B,S,D) fp32
#pragma unroll
    for (int d0 = 0; d0 < 4; ++d0)
#pragma unroll
        for (int r = 0; r < 4; ++r) {
            const int row = q0 + w * 16 + quad * 4 + r;
            ctx[((size_t)(b * SS + row)) * DD + h * HDIM + d0 * 16 + l15] =
                cacc[d0][r] / l_i[r];
        }
}

// ---------------------------------------------------------------------------
// Kernel 3: output projection ctx @ wo^T + bo -> (B*S, D) row-major.
// ---------------------------------------------------------------------------
__global__ __launch_bounds__(256) void gemm_out(
    const float* __restrict__ A, const float* __restrict__ W,
    const float* __restrict__ bias, float* __restrict__ Out)
{
    __shared__ float As[64][17];
    __shared__ float Ws[64][17];

    const int tid = threadIdx.x;
    const int tx = tid % 16, ty = tid / 16;
    const int row0 = blockIdx.x * 64;
    const int col0 = blockIdx.y * 64;

    const int lr = tid / 4;
    const int lc = (tid % 4) * 4;

    float acc[4][4] = {};

    for (int k0 = 0; k0 < KDIM; k0 += 16) {
        float4 a4 = *(const float4*)(A + (size_t)(row0 + lr) * KDIM + k0 + lc);
        float4 w4 = *(const float4*)(W + (size_t)(col0 + lr) * KDIM + k0 + lc);
        As[lr][lc + 0] = a4.x; As[lr][lc + 1] = a4.y;
        As[lr][lc + 2] = a4.z; As[lr][lc + 3] = a4.w;
        Ws[lr][lc + 0] = w4.x; Ws[lr][lc + 1] = w4.y;
        Ws[lr][lc + 2] = w4.z; Ws[lr][lc + 3] = w4.w;
        __syncthreads();
#pragma unroll
        for (int kk = 0; kk < 16; ++kk) {
            float a[4], w[4];
#pragma unroll
            for (int i = 0; i < 4; ++i) a[i] = As[ty * 4 + i][kk];
#pragma unroll
            for (int j = 0; j < 4; ++j) w[j] = Ws[tx * 4 + j][kk];
#pragma unroll
            for (int i = 0; i < 4; ++i)
#pragma unroll
                for (int j = 0; j < 4; ++j) acc[i][j] += a[i] * w[j];
        }
        __syncthreads();
    }

#pragma unroll
    for (int i = 0; i < 4; ++i) {
        const int t = row0 + ty * 4 + i;
#pragma unroll
        for (int j = 0; j < 4; ++j) {
            const int c = col0 + tx * 4 + j;
            Out[(size_t)t * DD + c] = acc[i][j] + bias[c];
        }
    }
}

// ---------------------------------------------------------------------------
// Kernel 4: residual add + RMSNorm. One block per token.
// ---------------------------------------------------------------------------
__global__ __launch_bounds__(256) void resid_rmsnorm(
    const float* __restrict__ proj, const float* __restrict__ hs,
    const float* __restrict__ scale, float* __restrict__ out)
{
    const int t = blockIdx.x;
    const int tid = threadIdx.x;
    const size_t base = (size_t)t * DD + tid * 4;

    const float4 p4 = *(const float4*)(proj + base);
    const float4 h4 = *(const float4*)(hs + base);
    float x0 = p4.x + h4.x, x1 = p4.y + h4.y, x2 = p4.z + h4.z, x3 = p4.w + h4.w;
    float ss = x0 * x0 + x1 * x1 + x2 * x2 + x3 * x3;

#pragma unroll
    for (int off = 1; off < 64; off <<= 1) ss += __shfl_xor(ss, off);

    __shared__ float wsum[4];
    if ((tid & 63) == 0) wsum[tid >> 6] = ss;
    __syncthreads();
    const float total = wsum[0] + wsum[1] + wsum[2] + wsum[3];
    const float inv = 1.f / (sqrtf(total * (1.f / DD)) + EPSF);

    const float4 s4 = *(const float4*)(scale + tid * 4);
    float4 o;
    o.x = s4.x * x0 * inv;
    o.y = s4.y * x1 * inv;
    o.z = s4.z * x2 * inv;
    o.w = s4.w * x3 * inv;
    *(float4*)(out + base) = o;
}

// ---------------------------------------------------------------------------
extern "C" void kernel_launch(void* const* d_in, const int* in_sizes, int n_in,
                              void* d_out, int out_size, void* d_ws, size_t ws_size,
                              hipStream_t stream) {
    const float* hs    = (const float*)d_in[0];
    const float* sinp  = (const float*)d_in[1];
    const float* cosp  = (const float*)d_in[2];
    const float* wq    = (const float*)d_in[3];
    const float* wk    = (const float*)d_in[4];
    const float* wv    = (const float*)d_in[5];
    const float* wo    = (const float*)d_in[6];
    const float* bo    = (const float*)d_in[7];
    const float* scale = (const float*)d_in[8];
    float* out = (float*)d_out;

    unsigned char* wsb = (unsigned char*)d_ws;
    const size_t MAT = (size_t)BB * SS * DD;        // 4,194,304 elements
    ushort* Qb  = (ushort*)wsb;                     // 8 MB bf16 (B,H,S,HD)
    ushort* Kb  = Qb + MAT;                         // 8 MB
    ushort* Vtb = Kb + MAT;                         // 8 MB bf16 (B,H,HD,S)
    float* ctxb = (float*)(wsb + 3 * MAT * sizeof(ushort));   // 16 MB (B,S,D)
    float* proj = ctxb + MAT;                       // 16 MB (B,S,D)

    gemm_qkv_rope<<<dim3(64, 16, 3), 256, 0, stream>>>(hs, wq, wk, wv, sinp, cosp,
                                                       Qb, Kb, Vtb);
    attn_mfma<<<dim3(SS / 64, BB * HH), 256, 0, stream>>>(Qb, Kb, Vtb, ctxb);
    gemm_out<<<dim3(64, 16), 256, 0, stream>>>(ctxb, wo, bo, proj);
    resid_rmsnorm<<<dim3(BB * SS), 256, 0, stream>>>(proj, hs, scale, out);
}

// Round 3
// 444.798 us; speedup vs baseline: 5.5853x; 2.3646x over previous
//
#include <hip/hip_runtime.h>
#include <cmath>

#define BB 2
#define SS 2048
#define DD 1024
#define HH 16
#define HDIM 64
#define KDIM 1024
#define EPSF 1e-8f

typedef __attribute__((ext_vector_type(8))) short bf16x8;
typedef __attribute__((ext_vector_type(4))) float f32x4;

__device__ __forceinline__ ushort f2bf(float x) {
    unsigned u = __builtin_bit_cast(unsigned, x);
    u += 0x7FFFu + ((u >> 16) & 1u);   // RNE
    return (ushort)(u >> 16);
}

__device__ __forceinline__ void gload_lds16(const ushort* g, ushort* l) {
    __builtin_amdgcn_global_load_lds(
        (const __attribute__((address_space(1))) unsigned*)g,
        (__attribute__((address_space(3))) unsigned*)l, 16, 0, 0);
}

// ---------------------------------------------------------------------------
// fp32 -> bf16 conversion (grid covers n4 float4 groups)
// ---------------------------------------------------------------------------
__global__ __launch_bounds__(256) void conv_bf16(
    const float* __restrict__ src, ushort* __restrict__ dst, int n4)
{
    const int i = blockIdx.x * 256 + threadIdx.x;
    if (i < n4) {
        const float4 v = ((const float4*)src)[i];
        ushort4 o;
        o.x = f2bf(v.x); o.y = f2bf(v.y); o.z = f2bf(v.z); o.w = f2bf(v.w);
        ((ushort4*)dst)[i] = o;
    }
}

// ---------------------------------------------------------------------------
// Kernel 1: fused QKV projection, bf16 MFMA (m97 structure: 128x128 tile,
// BK=32, global_load_lds width-16 staging, ds_read_b128 fragments).
// blockIdx.y in [0,24): y/8 selects {wq,wk,wv}, y%8 the 128-col strip.
// RoPE fused in epilogue via shfl_xor(.,1) (adjacent cols = adjacent lanes).
// Q,K -> (B,H,S,HD) bf16; V -> (B,H,HD,S) bf16 (transposed for PV B-frags).
// ---------------------------------------------------------------------------
__global__ __launch_bounds__(256) void gemm_qkv_mfma(
    const ushort* __restrict__ A,
    const ushort* __restrict__ Wq, const ushort* __restrict__ Wk,
    const ushort* __restrict__ Wv,
    const float* __restrict__ sinp, const float* __restrict__ cosp,
    ushort* __restrict__ Qb, ushort* __restrict__ Kb, ushort* __restrict__ Vtb)
{
    const int cb = blockIdx.y;
    const int z = cb >> 3;
    const int col0 = (cb & 7) * 128;
    const ushort* W = (z == 0) ? Wq : (z == 1) ? Wk : Wv;
    ushort* O = (z == 0) ? Qb : (z == 1) ? Kb : Vtb;
    const int row0 = blockIdx.x * 128;

    __shared__ __align__(16) ushort As[128 * 32];
    __shared__ __align__(16) ushort Bs[128 * 32];

    const int tid = threadIdx.x;
    const int w = tid >> 6, lane = tid & 63;
    const int quad = lane >> 4, l15 = lane & 15;
    const int m_off = (w >> 1) * 64, n_off = (w & 1) * 64;

    f32x4 acc[4][4] = {};

    for (int k0 = 0; k0 < KDIM; k0 += 32) {
#pragma unroll
        for (int it = 0; it < 2; ++it) {
            const int L = (it * 4 + w) * 64 + lane;       // 0..511
            const int r = L >> 2, c8 = (L & 3) * 8;
            gload_lds16(A + (size_t)(row0 + r) * KDIM + k0 + c8, &As[L * 8]);
            gload_lds16(W + (size_t)(col0 + r) * KDIM + k0 + c8, &Bs[L * 8]);
        }
        __syncthreads();
        bf16x8 af[4], bfr[4];
#pragma unroll
        for (int i = 0; i < 4; ++i) {
            af[i]  = *(const bf16x8*)&As[(m_off + i * 16 + l15) * 32 + quad * 8];
            bfr[i] = *(const bf16x8*)&Bs[(n_off + i * 16 + l15) * 32 + quad * 8];
        }
#pragma unroll
        for (int i = 0; i < 4; ++i)
#pragma unroll
            for (int j = 0; j < 4; ++j)
                acc[i][j] = __builtin_amdgcn_mfma_f32_16x16x32_bf16(
                    af[i], bfr[j], acc[i][j], 0, 0, 0);
        __syncthreads();
    }

    // Epilogue: RoPE + scatter.  C layout: col = l15, row = quad*4 + reg.
    const int b = (row0 + m_off) / SS;          // 64-row strip never crosses batch
#pragma unroll
    for (int mi = 0; mi < 4; ++mi) {
        const int mrow = row0 + m_off + mi * 16 + quad * 4;
#pragma unroll
        for (int ni = 0; ni < 4; ++ni) {
            const int c = col0 + n_off + ni * 16 + l15;
            const int h = c >> 6, e = c & 63;
            const int bh = b * HH + h;
            float outv[4];
#pragma unroll
            for (int r = 0; r < 4; ++r) {
                const int s = (mrow + r) & (SS - 1);
                const float sv = sinp[s * (HDIM / 2) + (e >> 1)];
                const float cv = cosp[s * (HDIM / 2) + (e >> 1)];
                const float v = acc[mi][ni][r];
                const float vp = __shfl_xor(v, 1);
                outv[r] = (l15 & 1) ? (v * cv + vp * sv) : (v * cv - vp * sv);
            }
            if (z < 2) {
#pragma unroll
                for (int r = 0; r < 4; ++r) {
                    const int s = (mrow + r) & (SS - 1);
                    const ushort mine = f2bf(outv[r]);
                    const ushort part = (ushort)__shfl_xor((int)mine, 1);
                    if (!(l15 & 1))
                        *(unsigned*)(O + ((size_t)(bh * SS + s)) * HDIM + e) =
                            (unsigned)mine | ((unsigned)part << 16);
                }
            } else {
                ushort4 pk;
                pk.x = f2bf(outv[0]); pk.y = f2bf(outv[1]);
                pk.z = f2bf(outv[2]); pk.w = f2bf(outv[3]);
                const int s0 = mrow & (SS - 1);
                *(ushort4*)(O + ((size_t)(bh * HDIM + e)) * SS + s0) = pk;
            }
        }
    }
}

// ---------------------------------------------------------------------------
// Kernel 2: flash attention with bf16 MFMA (16x16x32). ctx out: bf16 (B,S,D).
// ---------------------------------------------------------------------------
__global__ __launch_bounds__(256) void attn_mfma(
    const ushort* __restrict__ Qb, const ushort* __restrict__ Kb,
    const ushort* __restrict__ Vtb, ushort* __restrict__ ctx)
{
    const int bh = blockIdx.y;
    const int b = bh / HH, h = bh % HH;
    const int q0 = blockIdx.x * 64;
    const int tid = threadIdx.x;
    const int w = tid >> 6;
    const int lane = tid & 63;
    const int quad = lane >> 4;
    const int l15 = lane & 15;

    __shared__ __align__(16) float ps[64][68];

    const ushort* Qh = Qb  + (size_t)bh * SS * HDIM;
    const ushort* Kh = Kb  + (size_t)bh * SS * HDIM;
    const ushort* Vh = Vtb + (size_t)bh * HDIM * SS;

    const int qrow = q0 + w * 16 + l15;
    const bf16x8 qf0 = *(const bf16x8*)(Qh + (size_t)qrow * HDIM + quad * 8);
    const bf16x8 qf1 = *(const bf16x8*)(Qh + (size_t)qrow * HDIM + 32 + quad * 8);

    f32x4 cacc[4] = {{0,0,0,0},{0,0,0,0},{0,0,0,0},{0,0,0,0}};
    float m_i[4] = {-INFINITY, -INFINITY, -INFINITY, -INFINITY};
    float l_i[4] = {0.f, 0.f, 0.f, 0.f};

    for (int k0 = 0; k0 < SS; k0 += 64) {
        f32x4 sacc[4];
#pragma unroll
        for (int n0 = 0; n0 < 4; ++n0) {
            const ushort* kr = Kh + (size_t)(k0 + n0 * 16 + l15) * HDIM + quad * 8;
            const bf16x8 kf0 = *(const bf16x8*)(kr);
            const bf16x8 kf1 = *(const bf16x8*)(kr + 32);
            f32x4 s = {0.f, 0.f, 0.f, 0.f};
            s = __builtin_amdgcn_mfma_f32_16x16x32_bf16(qf0, kf0, s, 0, 0, 0);
            s = __builtin_amdgcn_mfma_f32_16x16x32_bf16(qf1, kf1, s, 0, 0, 0);
            sacc[n0] = s;
        }
#pragma unroll
        for (int r = 0; r < 4; ++r) {
            float mx = fmaxf(fmaxf(sacc[0][r], sacc[1][r]),
                             fmaxf(sacc[2][r], sacc[3][r]));
#pragma unroll
            for (int off = 1; off < 16; off <<= 1) mx = fmaxf(mx, __shfl_xor(mx, off));
            const float mnew = fmaxf(m_i[r], mx * 0.125f);
            const float alpha = __expf(m_i[r] - mnew);
            float ls = 0.f;
#pragma unroll
            for (int n0 = 0; n0 < 4; ++n0) {
                const float p = __expf(sacc[n0][r] * 0.125f - mnew);
                ps[w * 16 + quad * 4 + r][n0 * 16 + l15] = p;
                ls += p;
            }
#pragma unroll
            for (int off = 1; off < 16; off <<= 1) ls += __shfl_xor(ls, off);
            l_i[r] = l_i[r] * alpha + ls;
            m_i[r] = mnew;
#pragma unroll
            for (int d0 = 0; d0 < 4; ++d0) cacc[d0][r] *= alpha;
        }
#pragma unroll
        for (int step = 0; step < 2; ++step) {
            const float* pr = &ps[w * 16 + l15][step * 32 + quad * 8];
            const float4 p0 = *(const float4*)(pr);
            const float4 p1 = *(const float4*)(pr + 4);
            union { ushort us[8]; bf16x8 v; } pu;
            pu.us[0] = f2bf(p0.x); pu.us[1] = f2bf(p0.y);
            pu.us[2] = f2bf(p0.z); pu.us[3] = f2bf(p0.w);
            pu.us[4] = f2bf(p1.x); pu.us[5] = f2bf(p1.y);
            pu.us[6] = f2bf(p1.z); pu.us[7] = f2bf(p1.w);
#pragma unroll
            for (int d0 = 0; d0 < 4; ++d0) {
                const bf16x8 vf = *(const bf16x8*)(
                    Vh + (size_t)(d0 * 16 + l15) * SS + k0 + step * 32 + quad * 8);
                cacc[d0] = __builtin_amdgcn_mfma_f32_16x16x32_bf16(pu.v, vf, cacc[d0], 0, 0, 0);
            }
        }
    }

#pragma unroll
    for (int d0 = 0; d0 < 4; ++d0)
#pragma unroll
        for (int r = 0; r < 4; ++r) {
            const int row = q0 + w * 16 + quad * 4 + r;
            ctx[((size_t)(b * SS + row)) * DD + h * HDIM + d0 * 16 + l15] =
                f2bf(cacc[d0][r] / l_i[r]);
        }
}

// ---------------------------------------------------------------------------
// Kernel 3: output projection, bf16 MFMA, + bias, fp32 out (B*S, D).
// ---------------------------------------------------------------------------
__global__ __launch_bounds__(256) void gemm_out_mfma(
    const ushort* __restrict__ A, const ushort* __restrict__ W,
    const float* __restrict__ bias, float* __restrict__ Out)
{
    const int row0 = blockIdx.x * 128;
    const int col0 = blockIdx.y * 128;

    __shared__ __align__(16) ushort As[128 * 32];
    __shared__ __align__(16) ushort Bs[128 * 32];

    const int tid = threadIdx.x;
    const int w = tid >> 6, lane = tid & 63;
    const int quad = lane >> 4, l15 = lane & 15;
    const int m_off = (w >> 1) * 64, n_off = (w & 1) * 64;

    f32x4 acc[4][4] = {};

    for (int k0 = 0; k0 < KDIM; k0 += 32) {
#pragma unroll
        for (int it = 0; it < 2; ++it) {
            const int L = (it * 4 + w) * 64 + lane;
            const int r = L >> 2, c8 = (L & 3) * 8;
            gload_lds16(A + (size_t)(row0 + r) * KDIM + k0 + c8, &As[L * 8]);
            gload_lds16(W + (size_t)(col0 + r) * KDIM + k0 + c8, &Bs[L * 8]);
        }
        __syncthreads();
        bf16x8 af[4], bfr[4];
#pragma unroll
        for (int i = 0; i < 4; ++i) {
            af[i]  = *(const bf16x8*)&As[(m_off + i * 16 + l15) * 32 + quad * 8];
            bfr[i] = *(const bf16x8*)&Bs[(n_off + i * 16 + l15) * 32 + quad * 8];
        }
#pragma unroll
        for (int i = 0; i < 4; ++i)
#pragma unroll
            for (int j = 0; j < 4; ++j)
                acc[i][j] = __builtin_amdgcn_mfma_f32_16x16x32_bf16(
                    af[i], bfr[j], acc[i][j], 0, 0, 0);
        __syncthreads();
    }

#pragma unroll
    for (int mi = 0; mi < 4; ++mi) {
        const int mrow = row0 + m_off + mi * 16 + quad * 4;
#pragma unroll
        for (int ni = 0; ni < 4; ++ni) {
            const int c = col0 + n_off + ni * 16 + l15;
            const float bv = bias[c];
#pragma unroll
            for (int r = 0; r < 4; ++r)
                Out[(size_t)(mrow + r) * DD + c] = acc[mi][ni][r] + bv;
        }
    }
}

// ---------------------------------------------------------------------------
// Kernel 4: residual add + RMSNorm. One block per token.
// ---------------------------------------------------------------------------
__global__ __launch_bounds__(256) void resid_rmsnorm(
    const float* __restrict__ proj, const float* __restrict__ hs,
    const float* __restrict__ scale, float* __restrict__ out)
{
    const int t = blockIdx.x;
    const int tid = threadIdx.x;
    const size_t base = (size_t)t * DD + tid * 4;

    const float4 p4 = *(const float4*)(proj + base);
    const float4 h4 = *(const float4*)(hs + base);
    float x0 = p4.x + h4.x, x1 = p4.y + h4.y, x2 = p4.z + h4.z, x3 = p4.w + h4.w;
    float ss = x0 * x0 + x1 * x1 + x2 * x2 + x3 * x3;

#pragma unroll
    for (int off = 1; off < 64; off <<= 1) ss += __shfl_xor(ss, off);

    __shared__ float wsum[4];
    if ((tid & 63) == 0) wsum[tid >> 6] = ss;
    __syncthreads();
    const float total = wsum[0] + wsum[1] + wsum[2] + wsum[3];
    const float inv = 1.f / (sqrtf(total * (1.f / DD)) + EPSF);

    const float4 s4 = *(const float4*)(scale + tid * 4);
    float4 o;
    o.x = s4.x * x0 * inv;
    o.y = s4.y * x1 * inv;
    o.z = s4.z * x2 * inv;
    o.w = s4.w * x3 * inv;
    *(float4*)(out + base) = o;
}

// ---------------------------------------------------------------------------
extern "C" void kernel_launch(void* const* d_in, const int* in_sizes, int n_in,
                              void* d_out, int out_size, void* d_ws, size_t ws_size,
                              hipStream_t stream) {
    const float* hs    = (const float*)d_in[0];
    const float* sinp  = (const float*)d_in[1];
    const float* cosp  = (const float*)d_in[2];
    const float* wq    = (const float*)d_in[3];
    const float* wk    = (const float*)d_in[4];
    const float* wv    = (const float*)d_in[5];
    const float* wo    = (const float*)d_in[6];
    const float* bo    = (const float*)d_in[7];
    const float* scale = (const float*)d_in[8];
    float* out = (float*)d_out;

    unsigned char* wsb = (unsigned char*)d_ws;
    const size_t MAT = (size_t)BB * SS * DD;   // 4,194,304 elements
    const size_t WN  = (size_t)DD * DD;        // 1,048,576 elements
    ushort* Abf = (ushort*)wsb;                         // 8 MB
    ushort* Wqb = Abf + MAT;                            // 2 MB
    ushort* Wkb = Wqb + WN;
    ushort* Wvb = Wkb + WN;
    ushort* Wob = Wvb + WN;
    ushort* Qb  = Wob + WN;                             // 8 MB (B,H,S,HD)
    ushort* Kb  = Qb + MAT;
    ushort* Vtb = Kb + MAT;                             // (B,H,HD,S)
    ushort* ctxb = Vtb + MAT;                           // 8 MB (B,S,D) bf16
    float* proj = (float*)(ctxb + MAT);                 // 16 MB

    conv_bf16<<<dim3((int)(MAT / 4 / 256)), 256, 0, stream>>>(hs, Abf, (int)(MAT / 4));
    conv_bf16<<<dim3((int)(WN / 4 / 256)), 256, 0, stream>>>(wq, Wqb, (int)(WN / 4));
    conv_bf16<<<dim3((int)(WN / 4 / 256)), 256, 0, stream>>>(wk, Wkb, (int)(WN / 4));
    conv_bf16<<<dim3((int)(WN / 4 / 256)), 256, 0, stream>>>(wv, Wvb, (int)(WN / 4));
    conv_bf16<<<dim3((int)(WN / 4 / 256)), 256, 0, stream>>>(wo, Wob, (int)(WN / 4));

    gemm_qkv_mfma<<<dim3(32, 24), 256, 0, stream>>>(Abf, Wqb, Wkb, Wvb,
                                                    sinp, cosp, Qb, Kb, Vtb);
    attn_mfma<<<dim3(SS / 64, BB * HH), 256, 0, stream>>>(Qb, Kb, Vtb, ctxb);
    gemm_out_mfma<<<dim3(32, 8), 256, 0, stream>>>(ctxb, Wob, bo, proj);
    resid_rmsnorm<<<dim3(BB * SS), 256, 0, stream>>>(proj, hs, scale, out);
}